// Round 6
// baseline (126.413 us; speedup 1.0000x reference)
//
#include <hip/hip_runtime.h>
#include <hip/hip_bf16.h>

#define N_ROWS 4096
#define D_DIM  768
#define MARGIN 1.0f
#define EPS_F  1e-12f

typedef __bf16 bf16x8 __attribute__((ext_vector_type(8)));
typedef float  f32x4  __attribute__((ext_vector_type(4)));

// async global->LDS DMA, 16 B per lane; LDS dst = wave-uniform base + lane*16
#define GLD16(gp, lp)                                                          \
    __builtin_amdgcn_global_load_lds(                                         \
        (const __attribute__((address_space(1))) void*)(gp),                  \
        (__attribute__((address_space(3))) void*)(lp), 16, 0, 0)

// ---------------------------------------------------------------------------
// Kernel 1: per-row sum of squares (fp32) + bf16 cast, one wave per row.
// ---------------------------------------------------------------------------
__global__ __launch_bounds__(256) void prep_kernel(const float* __restrict__ emb,
                                                   unsigned short* __restrict__ ebf,
                                                   float* __restrict__ sq) {
    const int wave = threadIdx.x >> 6;
    const int lane = threadIdx.x & 63;
    const int row  = blockIdx.x * 4 + wave;

    const float4* rp = (const float4*)(emb + (size_t)row * D_DIM);
    unsigned short* op = ebf + (size_t)row * D_DIM;

    float s = 0.f;
#pragma unroll
    for (int t = 0; t < 3; ++t) {
        const int idx = lane + t * 64;
        float4 v = rp[idx];
        s += v.x * v.x + v.y * v.y + v.z * v.z + v.w * v.w;
        union { ushort4 u4; __hip_bfloat16 h[4]; } o;
        o.h[0] = __float2bfloat16(v.x);
        o.h[1] = __float2bfloat16(v.y);
        o.h[2] = __float2bfloat16(v.z);
        o.h[3] = __float2bfloat16(v.w);
        *(ushort4*)(op + idx * 4) = o.u4;
    }
    for (int off = 32; off; off >>= 1) s += __shfl_down(s, off, 64);
    if (lane == 0) sq[row] = s;
}

// ---------------------------------------------------------------------------
// Kernel 2: A-panel-resident Gram + fused loss.
// Block = (row-panel ti, group of 4 j-tiles); each of 4 waves computes one
// 64x64 tile. A panel (64 x 384 per phase, 48 KB) staged ONCE per K-half via
// GLD16 with the 0-conflict 128B-row XOR-swizzle layout (6 super-chunks of
// [64 rows x 64 k]). B-frags load DIRECTLY global->register with a
// distance-2 software pipeline: no per-chunk LDS, no per-chunk barriers.
// 544 blocks, 2 blocks/CU (LDS 48KB) -> 8 waves/CU.
// Off-diagonal tiles weighted x2; diagonal skips i==j. Scale 1/(N*(N-1)).
// ---------------------------------------------------------------------------
__global__ __launch_bounds__(256, 2) void pair_kernel(const __hip_bfloat16* __restrict__ ebf_,
                                                      const float* __restrict__ sq,
                                                      const int* __restrict__ labels,
                                                      float* __restrict__ out) {
    const int tid  = threadIdx.x;
    const int lane = tid & 63;
    const int wave = tid >> 6;
    const int qd   = lane >> 4;
    const int ln16 = lane & 15;
    const int l7   = lane & 7;

    // ---- block decode: (ti, j-group) ----
    int b = blockIdx.x, ti = 0;
    for (;;) { const int ng = (64 - ti + 3) >> 2; if (b < ng) break; b -= ng; ++ti; }
    const int i0 = ti * 64;
    int tj = ti + b * 4 + wave;
    const bool active = (tj < 64);
    if (!active) tj = 63;              // clamped duplicate; weight 0 later
    const int j0 = tj * 64;

    // 6 super-chunks of [64 rows][64 k], row stride 64 elems (128 B) = 48 KB
    __shared__ __align__(16) unsigned short panel[6 * 4096];

    const unsigned short* ebf = (const unsigned short*)ebf_;

    f32x4 acc[4][4];
#pragma unroll
    for (int m = 0; m < 4; ++m)
#pragma unroll
        for (int n = 0; n < 4; ++n) acc[m][n] = (f32x4){0.f, 0.f, 0.f, 0.f};

    // staging lane map: lane -> row octet-offset gr, swizzled global granule gg
    const int gr = lane >> 3;          // 0..7
    const int gg = l7 ^ gr;            // LDS granule l7 holds global granule l7^gr

#define LOADB(dst, c)                                                          \
    do {                                                                       \
        _Pragma("unroll")                                                      \
        for (int n_ = 0; n_ < 4; ++n_)                                         \
            (dst)[n_] = *(const bf16x8*)&ebf[(size_t)(j0 + n_ * 16 + ln16) *   \
                        D_DIM + kbase + (c) * 32 + qd * 8];                    \
    } while (0)

#define READA(dst, c)                                                          \
    do {                                                                       \
        const int sc_ = (c) >> 1;                                              \
        const int gA_ = ((((c) & 1) << 2) + qd) ^ l7;                          \
        _Pragma("unroll")                                                      \
        for (int m_ = 0; m_ < 4; ++m_)                                         \
            (dst)[m_] = *(const bf16x8*)&panel[sc_ * 4096 +                    \
                        (m_ * 16 + ln16) * 64 + gA_ * 8];                      \
    } while (0)

#pragma unroll
    for (int phase = 0; phase < 2; ++phase) {
        const int kbase = phase * 384;

        __syncthreads();               // phase 1: prior A reads done
        // stage 48 KB: 48 GLD16 insts, 12 per wave: t = wave*12 + i
#pragma unroll
        for (int i = 0; i < 12; ++i) {
            const int t  = wave * 12 + i;
            const int sc = t >> 3;     // super-chunk 0..5
            const int jr = t & 7;      // row octet 0..7
            GLD16(ebf + (size_t)(i0 + jr * 8 + gr) * D_DIM + kbase + sc * 64 + gg * 8,
                  panel + sc * 4096 + jr * 512);
        }
        __syncthreads();               // vmcnt(0) drained: panel ready

        // ---- 12 chunks, B distance-2 / A distance-1 register pipeline ----
        bf16x8 Bb[3][4], Ab[2][4];
        LOADB(Bb[0], 0);
        LOADB(Bb[1], 1);
        READA(Ab[0], 0);
#pragma unroll
        for (int c = 0; c < 12; ++c) {
            if (c + 2 < 12) LOADB(Bb[(c + 2) % 3], c + 2);
            if (c + 1 < 12) READA(Ab[(c + 1) & 1], c + 1);
            const bf16x8* A = Ab[c & 1];
            const bf16x8* B = Bb[c % 3];
#pragma unroll
            for (int m = 0; m < 4; ++m)
#pragma unroll
                for (int n = 0; n < 4; ++n)
                    acc[m][n] = __builtin_amdgcn_mfma_f32_16x16x32_bf16(
                        A[m], B[n], acc[m][n], 0, 0, 0);
        }
    }
#undef LOADB
#undef READA

    // ---- epilogue: contrastive loss per pair ----
    float psum = 0.f;
#pragma unroll
    for (int m = 0; m < 4; ++m) {
#pragma unroll
        for (int n = 0; n < 4; ++n) {
#pragma unroll
            for (int r = 0; r < 4; ++r) {
                const int gi = i0 + m * 16 + qd * 4 + r;   // C row
                const int gj = j0 + n * 16 + ln16;         // C col
                const float g = acc[m][n][r];
                float d2 = fmaxf(sq[gi] + sq[gj] - 2.0f * g, 0.0f);
                const float dist = sqrtf(d2 + EPS_F);
                const float h = fmaxf(MARGIN - dist, 0.0f);
                const float pl = (labels[gi] == labels[gj]) ? d2 : h * h;
                if (gi != gj) psum += pl;
            }
        }
    }

    for (int off = 32; off; off >>= 1) psum += __shfl_down(psum, off, 64);
    if (lane == 0) {
        const float wgt = !active ? 0.0f : (ti == tj ? 1.0f : 2.0f);
        const float scale = 1.0f / ((float)N_ROWS * (float)(N_ROWS - 1));
        atomicAdd(out, psum * wgt * scale);
    }
}

// ---------------------------------------------------------------------------
extern "C" void kernel_launch(void* const* d_in, const int* in_sizes, int n_in,
                              void* d_out, int out_size, void* d_ws, size_t ws_size,
                              hipStream_t stream) {
    const float* emb  = (const float*)d_in[0];
    const int* labels = (const int*)d_in[1];
    float* out        = (float*)d_out;

    unsigned short* ebf = (unsigned short*)d_ws;
    float* sq = (float*)((char*)d_ws + (size_t)N_ROWS * D_DIM * sizeof(unsigned short));

    hipMemsetAsync(d_out, 0, sizeof(float), stream);
    prep_kernel<<<N_ROWS / 4, 256, 0, stream>>>(emb, ebf, sq);

    // sum over ti of ceil((64-ti)/4) = 544 blocks
    pair_kernel<<<544, 256, 0, stream>>>((const __hip_bfloat16*)ebf, sq, labels, out);
}